// Round 1
// baseline (2783.393 us; speedup 1.0000x reference)
//
#include <hip/hip_runtime.h>
#include <hip/hip_bf16.h>
#include <stdint.h>

#define B_ 128
#define S_ 256
#define H_ 256

typedef __attribute__((ext_vector_type(8))) short short8;
typedef __attribute__((ext_vector_type(4))) float f32x4;

__device__ __forceinline__ short f2bf_s(float x){
    union { __hip_bfloat16 b; short s; } u; u.b = __float2bfloat16(x); return u.s;
}
__device__ __forceinline__ float bf2f_s(short s){
    union { __hip_bfloat16 b; short s2; } u; u.s2 = s; return __bfloat162float(u.b);
}
__device__ __forceinline__ void load_lds16(const void* g, void* l){
    __builtin_amdgcn_global_load_lds(
        (const __attribute__((address_space(1))) void*)g,
        (__attribute__((address_space(3))) void*)l, 16, 0, 0);
}
__device__ __forceinline__ float sigmoidf_(float x){
    return 1.0f / (1.0f + __expf(-x));
}

// ---------- conversion kernels ----------

// x [b*256+s][1024] f32 -> xin row (s*128+b), cols [0,1024) bf16 (row stride 2048)
// s-major xin => one 128-row U-GEMM tile == one timestep s.
__global__ void k_cvt_x(const float* __restrict__ x, short* __restrict__ xin){
    int q = blockIdx.x * blockDim.x + threadIdx.x;   // quad index, total 8388608
    if (q >= 8388608) return;
    const float4 v = ((const float4*)x)[q];
    int r = q >> 8;            // row b*256+s (256 quads per row)
    int c4 = (q & 255) << 2;
    int rp = (r & 255) * 128 + (r >> 8);   // s*128+b
    short4 o;
    o.x = f2bf_s(v.x); o.y = f2bf_s(v.y); o.z = f2bf_s(v.z); o.w = f2bf_s(v.w);
    *(short4*)(xin + (int64_t)rp * 2048 + c4) = o;
}

// stages [32768][67] f32 -> stagesP [32768][96] bf16 (zero pad), b-major
__global__ void k_cvt_stages(const float* __restrict__ st, short* __restrict__ sp){
    int i = blockIdx.x * blockDim.x + threadIdx.x;
    if (i >= 32768 * 96) return;
    int r = i / 96, k = i - r * 96;
    sp[i] = (k < 67) ? f2bf_s(st[(int64_t)r * 67 + k]) : (short)0;
}

// w [K][N] f32 -> wt [N][Kpad] bf16 (zero pad k>=K)
__global__ void k_transpose(const float* __restrict__ w, short* __restrict__ wt,
                            int K, int N, int Kpad){
    int i = blockIdx.x * blockDim.x + threadIdx.x;
    if (i >= N * Kpad) return;
    int n = i / Kpad, k = i - n * Kpad;
    wt[i] = (k < K) ? f2bf_s(w[(int64_t)k * N + n]) : (short)0;
}

// ---------- bf16 MFMA GEMM: C[M,N] = A[M,K] @ BT[N,K]^T + bias ----------
// flags: 1=relu, 2=store bf16 to Cb, 8=(with 2) permute row b*256+s -> s*128+b
__global__ __launch_bounds__(256) void k_gemm(
    const short* __restrict__ A, int lda,
    const short* __restrict__ BT, int ldb,
    const float* __restrict__ bias,
    int K, int flags,
    float* __restrict__ Cf, short* __restrict__ Cb, int ldc)
{
    __shared__ __align__(16) short At[128 * 32];
    __shared__ __align__(16) short Bt[128 * 32];
    const int tid = threadIdx.x;
    const int lane = tid & 63, w = tid >> 6;
    const int q = lane >> 4, m = lane & 15;
    const int wr = w >> 1, wc = w & 1;
    const int bm = blockIdx.y, bn = blockIdx.x;

    const short* Ablk = A + (int64_t)bm * 128 * lda;
    const short* Bblk = BT + (int64_t)bn * 128 * ldb;

    f32x4 acc[4][4] = {};

    for (int k0 = 0; k0 < K; k0 += 32){
#pragma unroll
        for (int call = 0; call < 2; ++call){
            int chunk = (call * 4 + w) * 64 + lane;
            int row = chunk >> 2, co = (chunk & 3) * 8;
            load_lds16(Ablk + (int64_t)row * lda + k0 + co, At + (call * 4 + w) * 512);
            load_lds16(Bblk + (int64_t)row * ldb + k0 + co, Bt + (call * 4 + w) * 512);
        }
        __syncthreads();
        short8 af[4], bfr[4];
#pragma unroll
        for (int mt = 0; mt < 4; ++mt)
            af[mt] = *(const short8*)(At + (wr * 64 + mt * 16 + m) * 32 + q * 8);
#pragma unroll
        for (int nt = 0; nt < 4; ++nt)
            bfr[nt] = *(const short8*)(Bt + (wc * 64 + nt * 16 + m) * 32 + q * 8);
#pragma unroll
        for (int mt = 0; mt < 4; ++mt)
#pragma unroll
            for (int nt = 0; nt < 4; ++nt)
                acc[mt][nt] = __builtin_amdgcn_mfma_f32_16x16x32_bf16(
                    af[mt], bfr[nt], acc[mt][nt], 0, 0, 0);
        __syncthreads();
    }

#pragma unroll
    for (int mt = 0; mt < 4; ++mt){
#pragma unroll
        for (int nt = 0; nt < 4; ++nt){
            int col = bn * 128 + wc * 64 + nt * 16 + m;
            float bv = bias[col];
#pragma unroll
            for (int rg = 0; rg < 4; ++rg){
                int row = bm * 128 + wr * 64 + mt * 16 + q * 4 + rg;
                float v = acc[mt][nt][rg] + bv;
                if (flags & 1) v = fmaxf(v, 0.0f);
                if (flags & 2){
                    int64_t orow = (flags & 8)
                        ? ((int64_t)(row & 255) * 128 + (row >> 8)) : (int64_t)row;
                    Cb[orow * ldc + col] = f2bf_s(v);
                } else {
                    Cf[(int64_t)row * ldc + col] = v;
                }
            }
        }
    }
}

// ---------- fused U-projection GEMM + TLSTM scan ----------
// blocks [0,256): scan, 8 row-groups x 32 col-groups (16 batch rows x 8 cells).
// blocks [256,2048): U-GEMM tiles bm in [32,256), bn in [0,8). u[0..31] comes
// from a pre-kernel. GEMM publishes u via relaxed-agent atomic stores (LLC
// write-through) + per-bm counter uprog[bm] (reaches 8). Scan gates each step
// on prefix-done (u_upto) with an acquire fence on advance.
//
// State exchange: ring of 2 slabs per array (hring/cring [2][128][256] u32,
// packed bf16 hi|lo). Bits 16..17 of each word (lo-bf16 mantissa LSBs, error
// ~2^-22 rel) carry tag = s&3. Consumers spin on the data itself with agent
// atomic u64 loads until every word's tag matches (s-1)&3 — tag+payload share
// one atomic word, so no counters, no separate signal round-trip. Ring-2 is
// safe: writing slab s+1 requires having observed all of slab s, which implies
// every peer finished reading slab s-1. Every 4th spin round falls back to
// fetch_add(p,0) (validated LLC-fresh RMW) so staleness can't hang us.
// Slabs are poisoned per-launch with never-matching tags (slot0=0x55 -> tag 1,
// slot1=0x00 -> tag 0; slot0 expects {0,2}, slot1 expects {1,3}).
//
// Wave roles per step: w0 = spin h + W_all tiles t=0,1 (48 mfma);
// w1 = spin c + W_d tile (24 mfma); w2/w3 = u gate/prefetch + pointwise +
// tagged stores + feat. Two barriers per step.
struct ScanSh {
    short wf_hi[3][8][64][8];
    short wf_lo[3][8][64][8];
    float Dg[3][16][17];
};
struct GemmSh { short At[128 * 32]; short Bt[128 * 32]; };

__global__ __launch_bounds__(256, 2) void k_fused(
    const short* __restrict__ xin, const short* __restrict__ UwT,
    const float* __restrict__ U_b,
    const float* __restrict__ W_all, const float* __restrict__ W_all_b,
    const float* __restrict__ W_d,   const float* __restrict__ W_d_b,
    float* uu,                        // [s][b][1024] f32 (written by gemm blocks, read by scan)
    const float* __restrict__ tsp,
    unsigned* __restrict__ uprog,     // [256] per-bm tile counters
    unsigned* __restrict__ hring,     // [2][128][256] packed bf16 hi|lo + tag
    unsigned* __restrict__ cring,     // [2][128][256]
    float* __restrict__ feat)         // [B][S][H]
{
    __shared__ __align__(16) union { ScanSh sc; GemmSh gm; } sh;
    const int tid = threadIdx.x;

    if (blockIdx.x >= 256){
        // ---------------- U-GEMM tile ----------------
        int gid = blockIdx.x - 256;
        const int bm = 32 + (gid >> 3), bn = gid & 7;
        const int lane = tid & 63, w = tid >> 6;
        const int q = lane >> 4, m = lane & 15;
        const int wr = w >> 1, wc = w & 1;
        const short* Ablk = xin + (int64_t)bm * 128 * 2048;
        const short* Bblk = UwT + (int64_t)bn * 128 * 2048;
        f32x4 acc[4][4] = {};
        for (int k0 = 0; k0 < 2048; k0 += 32){
#pragma unroll
            for (int call = 0; call < 2; ++call){
                int chunk = (call * 4 + w) * 64 + lane;
                int row = chunk >> 2, co = (chunk & 3) * 8;
                load_lds16(Ablk + (int64_t)row * 2048 + k0 + co, sh.gm.At + (call * 4 + w) * 512);
                load_lds16(Bblk + (int64_t)row * 2048 + k0 + co, sh.gm.Bt + (call * 4 + w) * 512);
            }
            __syncthreads();
            short8 af[4], bfr[4];
#pragma unroll
            for (int mt = 0; mt < 4; ++mt)
                af[mt] = *(const short8*)(sh.gm.At + (wr * 64 + mt * 16 + m) * 32 + q * 8);
#pragma unroll
            for (int nt = 0; nt < 4; ++nt)
                bfr[nt] = *(const short8*)(sh.gm.Bt + (wc * 64 + nt * 16 + m) * 32 + q * 8);
#pragma unroll
            for (int mt = 0; mt < 4; ++mt)
#pragma unroll
                for (int nt = 0; nt < 4; ++nt)
                    acc[mt][nt] = __builtin_amdgcn_mfma_f32_16x16x32_bf16(
                        af[mt], bfr[nt], acc[mt][nt], 0, 0, 0);
            __syncthreads();
        }
#pragma unroll
        for (int mt = 0; mt < 4; ++mt)
#pragma unroll
            for (int nt = 0; nt < 4; ++nt){
                int col = bn * 128 + wc * 64 + nt * 16 + m;
                float bv = U_b[col];
#pragma unroll
                for (int rg = 0; rg < 4; ++rg){
                    int row = bm * 128 + wr * 64 + mt * 16 + q * 4 + rg;
                    __hip_atomic_store(&uu[(int64_t)row * 1024 + col],
                                       acc[mt][nt][rg] + bv,
                                       __ATOMIC_RELAXED, __HIP_MEMORY_SCOPE_AGENT);
                }
            }
        __syncthreads();   // vmcnt drain: all atomic stores at LLC before signal
        if (tid == 0)
            __hip_atomic_fetch_add(&uprog[bm], 1u,
                                   __ATOMIC_RELAXED, __HIP_MEMORY_SCOPE_AGENT);
        return;
    }

    // ---------------- scan block ----------------
    __builtin_amdgcn_s_setprio(1);   // latency-critical waves beat co-resident gemm
    const int r = blockIdx.x >> 5, cg = blockIdx.x & 31;
    const int j0 = cg * 8, row0 = r * 16;

    // one-time: this WG's weight slice into LDS hi/lo bf16 B-fragments
    for (int idx = tid; idx < 3 * 8 * 64; idx += 256){
        int t = idx / 512;
        int kk = (idx >> 6) & 7;
        int ln = idx & 63;
        int qq = ln >> 4, nn = ln & 15;
#pragma unroll
        for (int jj = 0; jj < 8; ++jj){
            int k = kk * 32 + qq * 8 + jj;
            float v = 0.0f;
            if (t < 2){
                int ngl = (nn < 8) ? (t * 512 + j0 + nn) : (t * 512 + 256 + j0 + nn - 8);
                v = W_all[(int64_t)k * 1024 + ngl];
            } else if (nn < 8){
                v = W_d[(int64_t)k * 256 + j0 + nn];
            }
            short hi = f2bf_s(v);
            sh.sc.wf_hi[t][kk][ln][jj] = hi;
            sh.sc.wf_lo[t][kk][ln][jj] = f2bf_s(v - bf2f_s(hi));
        }
    }
    __syncthreads();

    const int lane = tid & 63, w = tid >> 6;
    const int q = lane >> 4, al15 = lane & 15;

    // owner-cell registers (w2/w3: tid2 in [0,128) owns (row0+tid2>>3, j0+(tid2&7)))
    const int tid2 = tid & 127;
    const int b_own = tid2 >> 3, jl_own = tid2 & 7;
    const int gb = row0 + b_own, gj = j0 + jl_own;
    float c_reg = 0.0f;
    float bf_ = 0, bi_ = 0, bo_ = 0, bg_ = 0, bd_ = 0;
    if (w >= 2){
        bf_ = W_all_b[gj];
        bi_ = W_all_b[256 + gj];
        bo_ = W_all_b[512 + gj];
        bg_ = W_all_b[768 + gj];
        bd_ = W_d_b[gj];
    }
    int u_upto = 32;   // u[0..31] guaranteed by pre-kernel (stream order)

    const unsigned long long TAGM = 0xFFFCFFFFFFFCFFFFULL;  // clear bits16,17 per u32

    for (int s = 0; s < 256; ++s){
        __syncthreads();   // A: prev-step Dg reads done before w0/w1 rewrite
        float uf = 0, ui = 0, uo = 0, ug = 0, tt = 0;

        if (w < 2){
            f32x4 acc0 = {0.f, 0.f, 0.f, 0.f}, acc1 = {0.f, 0.f, 0.f, 0.f};
            if (s > 0){
                const unsigned tagexp = (unsigned)((s - 1) & 3);
                unsigned long long* sp = (unsigned long long*)
                    ((w == 0 ? hring : cring) + (((s - 1) & 1) << 15) + (row0 + al15) * 256);
                unsigned long long d[32];
                for (unsigned round = 0; ; ++round){
                    if ((round & 3u) != 3u){
#pragma unroll
                        for (int kk = 0; kk < 8; ++kk)
#pragma unroll
                            for (int i = 0; i < 4; ++i)
                                d[kk * 4 + i] = __hip_atomic_load(
                                    &sp[kk * 16 + q * 4 + i],
                                    __ATOMIC_RELAXED, __HIP_MEMORY_SCOPE_AGENT);
                    } else {
                        // guaranteed-fresh RMW fallback round
#pragma unroll
                        for (int kk = 0; kk < 8; ++kk)
#pragma unroll
                            for (int i = 0; i < 4; ++i){
                                unsigned* pw = (unsigned*)&sp[kk * 16 + q * 4 + i];
                                unsigned lo = __hip_atomic_fetch_add(pw, 0u,
                                    __ATOMIC_RELAXED, __HIP_MEMORY_SCOPE_AGENT);
                                unsigned hi = __hip_atomic_fetch_add(pw + 1, 0u,
                                    __ATOMIC_RELAXED, __HIP_MEMORY_SCOPE_AGENT);
                                d[kk * 4 + i] = (unsigned long long)lo |
                                                ((unsigned long long)hi << 32);
                            }
                    }
                    bool bad = false;
#pragma unroll
                    for (int t2 = 0; t2 < 32; ++t2){
                        unsigned lo = (unsigned)d[t2], hi = (unsigned)(d[t2] >> 32);
                        bad |= (((lo >> 16) & 3u) != tagexp) | (((hi >> 16) & 3u) != tagexp);
                    }
                    if (__all(!bad)) break;
                }
                if (w == 0){
#pragma unroll
                    for (int kk = 0; kk < 8; ++kk){
                        unsigned long long q0 = d[kk*4+0] & TAGM, q1 = d[kk*4+1] & TAGM;
                        unsigned long long q2 = d[kk*4+2] & TAGM, q3 = d[kk*4+3] & TAGM;
                        unsigned w0_=(unsigned)q0, w1_=(unsigned)(q0>>32);
                        unsigned w2_=(unsigned)q1, w3_=(unsigned)(q1>>32);
                        unsigned w4_=(unsigned)q2, w5_=(unsigned)(q2>>32);
                        unsigned w6_=(unsigned)q3, w7_=(unsigned)(q3>>32);
                        union { short8 v; unsigned u32[4]; } ah, al;
                        ah.u32[0]=__builtin_amdgcn_perm(w1_,w0_,0x05040100u);
                        ah.u32[1]=__builtin_amdgcn_perm(w3_,w2_,0x05040100u);
                        ah.u32[2]=__builtin_amdgcn_perm(w5_,w4_,0x05040100u);
                        ah.u32[3]=__builtin_amdgcn_perm(w7_,w6_,0x05040100u);
                        al.u32[0]=__builtin_amdgcn_perm(w1_,w0_,0x07060302u);
                        al.u32[1]=__builtin_amdgcn_perm(w3_,w2_,0x07060302u);
                        al.u32[2]=__builtin_amdgcn_perm(w5_,w4_,0x07060302u);
                        al.u32[3]=__builtin_amdgcn_perm(w7_,w6_,0x07060302u);
                        short8 bh0 = *(const short8*)&sh.sc.wf_hi[0][kk][lane][0];
                        short8 bl0 = *(const short8*)&sh.sc.wf_lo[0][kk][lane][0];
                        short8 bh1 = *(const short8*)&sh.sc.wf_hi[1][kk][lane][0];
                        short8 bl1 = *(const short8*)&sh.sc.wf_lo[1][kk][lane][0];
                        acc0 = __builtin_amdgcn_mfma_f32_16x16x32_bf16(ah.v, bh0, acc0, 0,0,0);
                        acc0 = __builtin_amdgcn_mfma_f32_16x16x32_bf16(ah.v, bl0, acc0, 0,0,0);
                        acc0 = __builtin_amdgcn_mfma_f32_16x16x32_bf16(al.v, bh0, acc0, 0,0,0);
                        acc1 = __builtin_amdgcn_mfma_f32_16x16x32_bf16(ah.v, bh1, acc1, 0,0,0);
                        acc1 = __builtin_amdgcn_mfma_f32_16x16x32_bf16(ah.v, bl1, acc1, 0,0,0);
                        acc1 = __builtin_amdgcn_mfma_f32_16x16x32_bf16(al.v, bh1, acc1, 0,0,0);
                    }
                } else {
#pragma unroll
                    for (int kk = 0; kk < 8; ++kk){
                        unsigned long long q0 = d[kk*4+0] & TAGM, q1 = d[kk*4+1] & TAGM;
                        unsigned long long q2 = d[kk*4+2] & TAGM, q3 = d[kk*4+3] & TAGM;
                        unsigned w0_=(unsigned)q0, w1_=(unsigned)(q0>>32);
                        unsigned w2_=(unsigned)q1, w3_=(unsigned)(q1>>32);
                        unsigned w4_=(unsigned)q2, w5_=(unsigned)(q2>>32);
                        unsigned w6_=(unsigned)q3, w7_=(unsigned)(q3>>32);
                        union { short8 v; unsigned u32[4]; } ah, al;
                        ah.u32[0]=__builtin_amdgcn_perm(w1_,w0_,0x05040100u);
                        ah.u32[1]=__builtin_amdgcn_perm(w3_,w2_,0x05040100u);
                        ah.u32[2]=__builtin_amdgcn_perm(w5_,w4_,0x05040100u);
                        ah.u32[3]=__builtin_amdgcn_perm(w7_,w6_,0x05040100u);
                        al.u32[0]=__builtin_amdgcn_perm(w1_,w0_,0x07060302u);
                        al.u32[1]=__builtin_amdgcn_perm(w3_,w2_,0x07060302u);
                        al.u32[2]=__builtin_amdgcn_perm(w5_,w4_,0x07060302u);
                        al.u32[3]=__builtin_amdgcn_perm(w7_,w6_,0x07060302u);
                        short8 bh2 = *(const short8*)&sh.sc.wf_hi[2][kk][lane][0];
                        short8 bl2 = *(const short8*)&sh.sc.wf_lo[2][kk][lane][0];
                        acc0 = __builtin_amdgcn_mfma_f32_16x16x32_bf16(ah.v, bh2, acc0, 0,0,0);
                        acc0 = __builtin_amdgcn_mfma_f32_16x16x32_bf16(ah.v, bl2, acc0, 0,0,0);
                        acc0 = __builtin_amdgcn_mfma_f32_16x16x32_bf16(al.v, bh2, acc0, 0,0,0);
                    }
                }
            }
#pragma unroll
            for (int rg = 0; rg < 4; ++rg){
                if (w == 0){
                    sh.sc.Dg[0][q * 4 + rg][al15] = acc0[rg];
                    sh.sc.Dg[1][q * 4 + rg][al15] = acc1[rg];
                } else {
                    sh.sc.Dg[2][q * 4 + rg][al15] = acc0[rg];
                }
            }
        } else {
            // u prefix gate + prefetch (overlaps w0/w1 state spin)
            bool adv = false; unsigned rr = 0;
            while (u_upto <= s){
                unsigned v = ((rr & 3u) != 3u)
                    ? __hip_atomic_load(&uprog[u_upto],
                                        __ATOMIC_RELAXED, __HIP_MEMORY_SCOPE_AGENT)
                    : __hip_atomic_fetch_add(&uprog[u_upto], 0u,
                                        __ATOMIC_RELAXED, __HIP_MEMORY_SCOPE_AGENT);
                if (v >= 8u){ ++u_upto; adv = true; } else ++rr;
            }
            if (adv) __builtin_amdgcn_fence(__ATOMIC_ACQUIRE, "agent");
            const float* urow = uu + ((int64_t)s * 128 + gb) * 1024;
            uf = urow[gj];       ui = urow[256 + gj];
            uo = urow[512 + gj]; ug = urow[768 + gj];
            tt = tsp[gb * 256 + s];
        }
        __syncthreads();   // B: Dg ready

        if (w >= 2){
            float fpre = sh.sc.Dg[0][b_own][jl_own]     + uf + bf_;
            float ipre = sh.sc.Dg[0][b_own][8 + jl_own] + ui + bi_;
            float opre = sh.sc.Dg[1][b_own][jl_own]     + uo + bo_;
            float gpre = sh.sc.Dg[1][b_own][8 + jl_own] + ug + bg_;
            float spre = sh.sc.Dg[2][b_own][jl_own]     + bd_;

            float cs1 = tanhf(spre);
            float cadj = (c_reg - cs1) + cs1 * tt;
            float fg = sigmoidf_(fpre);
            float ig = sigmoidf_(ipre);
            float og = sigmoidf_(opre);
            float gg = sigmoidf_(gpre);
            float cn = fg * cadj + ig * gg;
            float hn = og * tanhf(cn);
            c_reg = cn;

            unsigned tag = (unsigned)(s & 3);
            short chi = f2bf_s(cn);
            unsigned short clo = (unsigned short)f2bf_s(cn - bf2f_s(chi));
            unsigned cword = (unsigned)(unsigned short)chi |
                             (((unsigned)((clo & 0xFFFCu) | tag)) << 16);
            short hhi = f2bf_s(hn);
            unsigned short hlo = (unsigned short)f2bf_s(hn - bf2f_s(hhi));
            unsigned hword = (unsigned)(unsigned short)hhi |
                             (((unsigned)((hlo & 0xFFFCu) | tag)) << 16);
            int off = ((s & 1) << 15) + gb * 256 + gj;
            __hip_atomic_store(&cring[off], cword,
                               __ATOMIC_RELAXED, __HIP_MEMORY_SCOPE_AGENT);
            __hip_atomic_store(&hring[off], hword,
                               __ATOMIC_RELAXED, __HIP_MEMORY_SCOPE_AGENT);
            __builtin_nontemporal_store(hn, &feat[((int64_t)gb * 256 + s) * 256 + gj]);
        }
    }
}

// ---------- classifier: out[r] = feat[r,:] . cls_w + cls_b ----------
__global__ __launch_bounds__(256) void k_cls(
    const float* __restrict__ feat, const float* __restrict__ cls_w,
    const float* __restrict__ cls_b, float* __restrict__ out)
{
    int tid = threadIdx.x, lane = tid & 63, w = tid >> 6;
    int row = blockIdx.x * 4 + w;
    float4 v  = ((const float4*)(feat + (int64_t)row * 256))[lane];
    float4 cw = ((const float4*)cls_w)[lane];
    float d = v.x * cw.x + v.y * cw.y + v.z * cw.z + v.w * cw.w;
#pragma unroll
    for (int off = 32; off > 0; off >>= 1)
        d += __shfl_down(d, off, 64);
    if (lane == 0) out[row] = d + cls_b[0];
}

extern "C" void kernel_launch(void* const* d_in, const int* in_sizes, int n_in,
                              void* d_out, int out_size, void* d_ws, size_t ws_size,
                              hipStream_t stream) {
    const float* x      = (const float*)d_in[0];
    const float* stages = (const float*)d_in[1];
    const float* tsp    = (const float*)d_in[2];
    const float* se_w1  = (const float*)d_in[3];
    const float* se_b1  = (const float*)d_in[4];
    const float* se_w2  = (const float*)d_in[5];
    const float* se_b2  = (const float*)d_in[6];
    const float* se_w3  = (const float*)d_in[7];
    const float* se_b3  = (const float*)d_in[8];
    const float* W_all  = (const float*)d_in[9];
    const float* W_allb = (const float*)d_in[10];
    const float* U_w    = (const float*)d_in[11];
    const float* U_b    = (const float*)d_in[12];
    const float* W_d    = (const float*)d_in[13];
    const float* W_d_b  = (const float*)d_in[14];
    const float* cls_w  = (const float*)d_in[15];
    const float* cls_b  = (const float*)d_in[16];
    (void)in_sizes; (void)n_in; (void)out_size; (void)ws_size;

    float* out  = (float*)d_out;          // [32768]
    float* feat = out + 32768;            // [32768][256]

    char* ws = (char*)d_ws;
    unsigned* uprog  = (unsigned*)(ws + 0);           // 1024 B used (memset 4096)
    unsigned* hring  = (unsigned*)(ws + 4096);        // 2*32768*4 = 262144
    unsigned* cring  = (unsigned*)(ws + 266240);      // 262144, ends 528384
    short*  stagesP  = (short*)  (ws + 532480);       // 32768*96*2    = 6291456
    short*  st1      = (short*)  (ws + 6823936);      // 32768*256*2   = 16777216
    short*  st2      = (short*)  (ws + 23601152);     // 32768*512*2   = 33554432
    short*  w1T      = (short*)  (ws + 57155584);     // 256*96*2
    short*  w2T      = (short*)  (ws + 57204736);     // 512*256*2
    short*  w3T      = (short*)  (ws + 57466880);     // 1024*512*2
    short*  UwT      = (short*)  (ws + 58515456);     // 1024*2048*2   = 4194304
    short*  xin      = (short*)  (ws + 62709760);     // 32768*2048*2  = 134217728 (s-major)
    float*  u        = (float*)  (ws + 196927488);    // 256*128*1024*4= 134217728

    // per-launch init: uprog=0; poison ring slabs with never-matching tags.
    // slot0 (expects tags {0,2}) poisoned 0x55 (tag 1); slot1 (expects {1,3})
    // poisoned 0x00 (tag 0). Ring is only ever accessed with atomic ops.
    hipMemsetAsync(uprog, 0, 4096, stream);
    hipMemsetAsync((char*)hring,          0x55, 131072, stream);
    hipMemsetAsync((char*)hring + 131072, 0x00, 131072, stream);
    hipMemsetAsync((char*)cring,          0x55, 131072, stream);
    hipMemsetAsync((char*)cring + 131072, 0x00, 131072, stream);

    // conversions (xin now s-major: row = s*128+b)
    k_cvt_x<<<8388608 / 256, 256, 0, stream>>>(x, xin);
    k_cvt_stages<<<(32768 * 96) / 256, 256, 0, stream>>>(stages, stagesP);
    k_transpose<<<(256 * 96) / 256, 256, 0, stream>>>(se_w1, w1T, 67, 256, 96);
    k_transpose<<<(512 * 256) / 256, 256, 0, stream>>>(se_w2, w2T, 256, 512, 256);
    k_transpose<<<(1024 * 512) / 256, 256, 0, stream>>>(se_w3, w3T, 512, 1024, 512);
    k_transpose<<<(1024 * 2048) / 256, 256, 0, stream>>>(U_w, UwT, 2048, 1024, 2048);

    // stage MLP (b-major chain), st3 stores permuted into s-major xin cols [1024,2048)
    k_gemm<<<dim3(2, 256), 256, 0, stream>>>(stagesP, 96, w1T, 96, se_b1, 96, 1 | 2,
                                             nullptr, st1, 256);
    k_gemm<<<dim3(4, 256), 256, 0, stream>>>(st1, 256, w2T, 256, se_b2, 256, 1 | 2,
                                             nullptr, st2, 512);
    k_gemm<<<dim3(8, 256), 256, 0, stream>>>(st2, 512, w3T, 512, se_b3, 512, 1 | 2 | 8,
                                             nullptr, xin + 1024, 2048);

    // u[0..31] pre-computed so the scan has runway before the fused gemm's
    // first tile wave retires (kernel boundary publishes it; plain stores ok)
    k_gemm<<<dim3(8, 32), 256, 0, stream>>>(xin, 2048, UwT, 2048, U_b, 2048, 0,
                                            u, nullptr, 1024);

    // fused: 256 scan blocks + 1792 U-GEMM blocks (bm 32..255)
    k_fused<<<2048, 256, 0, stream>>>(xin, UwT, U_b, W_all, W_allb, W_d, W_d_b,
                                      u, tsp, uprog, hring, cring, feat);

    // classifier
    k_cls<<<8192, 256, 0, stream>>>(feat, cls_w, cls_b, out);
}

// Round 2
// 2094.876 us; speedup vs baseline: 1.3287x; 1.3287x over previous
//
#include <hip/hip_runtime.h>
#include <hip/hip_bf16.h>
#include <stdint.h>

#define B_ 128
#define S_ 256
#define H_ 256

typedef __attribute__((ext_vector_type(8))) short short8;
typedef __attribute__((ext_vector_type(4))) float f32x4;

__device__ __forceinline__ short f2bf_s(float x){
    union { __hip_bfloat16 b; short s; } u; u.b = __float2bfloat16(x); return u.s;
}
__device__ __forceinline__ float bf2f_s(short s){
    union { __hip_bfloat16 b; short s2; } u; u.s2 = s; return __bfloat162float(u.b);
}
__device__ __forceinline__ void load_lds16(const void* g, void* l){
    __builtin_amdgcn_global_load_lds(
        (const __attribute__((address_space(1))) void*)g,
        (__attribute__((address_space(3))) void*)l, 16, 0, 0);
}
__device__ __forceinline__ float sigmoidf_(float x){
    return 1.0f / (1.0f + __expf(-x));
}

// ---------- conversion kernels ----------

// x [b*256+s][1024] f32 -> xin row (s*128+b), cols [0,1024) bf16 (row stride 2048)
// s-major xin => U-GEMM output rows are already [s][b] (plain f32 store).
__global__ void k_cvt_x(const float* __restrict__ x, short* __restrict__ xin){
    int q = blockIdx.x * blockDim.x + threadIdx.x;   // quad index, total 8388608
    if (q >= 8388608) return;
    const float4 v = ((const float4*)x)[q];
    int r = q >> 8;            // row b*256+s (256 quads per row)
    int c4 = (q & 255) << 2;
    int rp = (r & 255) * 128 + (r >> 8);   // s*128+b
    short4 o;
    o.x = f2bf_s(v.x); o.y = f2bf_s(v.y); o.z = f2bf_s(v.z); o.w = f2bf_s(v.w);
    *(short4*)(xin + (int64_t)rp * 2048 + c4) = o;
}

// stages [32768][67] f32 -> stagesP [32768][96] bf16 (zero pad), b-major
__global__ void k_cvt_stages(const float* __restrict__ st, short* __restrict__ sp){
    int i = blockIdx.x * blockDim.x + threadIdx.x;
    if (i >= 32768 * 96) return;
    int r = i / 96, k = i - r * 96;
    sp[i] = (k < 67) ? f2bf_s(st[(int64_t)r * 67 + k]) : (short)0;
}

// w [K][N] f32 -> wt [N][Kpad] bf16 (zero pad k>=K)
__global__ void k_transpose(const float* __restrict__ w, short* __restrict__ wt,
                            int K, int N, int Kpad){
    int i = blockIdx.x * blockDim.x + threadIdx.x;
    if (i >= N * Kpad) return;
    int n = i / Kpad, k = i - n * Kpad;
    wt[i] = (k < K) ? f2bf_s(w[(int64_t)k * N + n]) : (short)0;
}

// ---------- bf16 MFMA GEMM: C[M,N] = A[M,K] @ BT[N,K]^T + bias ----------
// flags: 1=relu, 2=store bf16 to Cb, 8=(with 2) permute row b*256+s -> s*128+b
__global__ __launch_bounds__(256) void k_gemm(
    const short* __restrict__ A, int lda,
    const short* __restrict__ BT, int ldb,
    const float* __restrict__ bias,
    int K, int flags,
    float* __restrict__ Cf, short* __restrict__ Cb, int ldc)
{
    __shared__ __align__(16) short At[128 * 32];
    __shared__ __align__(16) short Bt[128 * 32];
    const int tid = threadIdx.x;
    const int lane = tid & 63, w = tid >> 6;
    const int q = lane >> 4, m = lane & 15;
    const int wr = w >> 1, wc = w & 1;
    const int bm = blockIdx.y, bn = blockIdx.x;

    const short* Ablk = A + (int64_t)bm * 128 * lda;
    const short* Bblk = BT + (int64_t)bn * 128 * ldb;

    f32x4 acc[4][4] = {};

    for (int k0 = 0; k0 < K; k0 += 32){
#pragma unroll
        for (int call = 0; call < 2; ++call){
            int chunk = (call * 4 + w) * 64 + lane;
            int row = chunk >> 2, co = (chunk & 3) * 8;
            load_lds16(Ablk + (int64_t)row * lda + k0 + co, At + (call * 4 + w) * 512);
            load_lds16(Bblk + (int64_t)row * ldb + k0 + co, Bt + (call * 4 + w) * 512);
        }
        __syncthreads();
        short8 af[4], bfr[4];
#pragma unroll
        for (int mt = 0; mt < 4; ++mt)
            af[mt] = *(const short8*)(At + (wr * 64 + mt * 16 + m) * 32 + q * 8);
#pragma unroll
        for (int nt = 0; nt < 4; ++nt)
            bfr[nt] = *(const short8*)(Bt + (wc * 64 + nt * 16 + m) * 32 + q * 8);
#pragma unroll
        for (int mt = 0; mt < 4; ++mt)
#pragma unroll
            for (int nt = 0; nt < 4; ++nt)
                acc[mt][nt] = __builtin_amdgcn_mfma_f32_16x16x32_bf16(
                    af[mt], bfr[nt], acc[mt][nt], 0, 0, 0);
        __syncthreads();
    }

#pragma unroll
    for (int mt = 0; mt < 4; ++mt){
#pragma unroll
        for (int nt = 0; nt < 4; ++nt){
            int col = bn * 128 + wc * 64 + nt * 16 + m;
            float bv = bias[col];
#pragma unroll
            for (int rg = 0; rg < 4; ++rg){
                int row = bm * 128 + wr * 64 + mt * 16 + q * 4 + rg;
                float v = acc[mt][nt][rg] + bv;
                if (flags & 1) v = fmaxf(v, 0.0f);
                if (flags & 2){
                    int64_t orow = (flags & 8)
                        ? ((int64_t)(row & 255) * 128 + (row >> 8)) : (int64_t)row;
                    Cb[orow * ldc + col] = f2bf_s(v);
                } else {
                    Cf[(int64_t)row * ldc + col] = v;
                }
            }
        }
    }
}

// ---------- TLSTM scan (ring-tag protocol, separate dispatch) ----------
// 256 WGs = 8 row-groups (16 batch rows) x 32 col-groups (8 cells). Weights
// resident in LDS as bf16 hi/lo B-fragments (bf16x3 ~ f32 precision).
//
// State exchange: ring of 2 slabs per array (hring/cring [2][128][256] u32,
// packed bf16 hi|lo). Bits 16..17 of each word (lo-bf16 mantissa LSBs, rel
// error ~2^-22) carry tag = s&3. Consumers spin on the data itself with
// agent-scope atomic u64 loads (bypass non-coherent XCD L2, read at LLC)
// until every word's tag matches — tag and payload share one atomic word, so
// publication is free: NO counters, NO drain barrier, NO signal round-trip.
// Ring-2 safety: a WG writes slab s+1 only after observing all of slab s,
// which implies every peer (same row-group) finished reading slab s-1.
// Tag mod 4 + slot parity disambiguates s from s+-2. Every 8th spin round
// uses fetch_add(p,0) (validated LLC-fresh RMW) so staleness cannot hang.
// Slabs poisoned per-launch with never-matching tags (slot0=0x55 -> tag 1,
// expects {0,2}; slot1=0x00 -> tag 0, expects {1,3}).
//
// Wave roles per step: w0 = spin h + BOTH W_all tiles (48 mfma; h read once);
// w1 = spin c + W_d tile (24 mfma); w2/w3 = u/tsp prefetch (overlaps spins)
// + pointwise + tagged stores + feat. Two barriers per step.
__global__ __launch_bounds__(256, 1) void k_scan(
    const float* __restrict__ W_all, const float* __restrict__ W_all_b,
    const float* __restrict__ W_d,   const float* __restrict__ W_d_b,
    const float* __restrict__ u,     const float* __restrict__ tsp,
    unsigned* __restrict__ hring,    // [2][128][256] packed bf16 hi|lo + tag
    unsigned* __restrict__ cring,    // [2][128][256]
    float* __restrict__ feat)        // [B][S][H]
{
    __shared__ __align__(16) short wf_hi[3][8][64][8];
    __shared__ __align__(16) short wf_lo[3][8][64][8];
    __shared__ float Dg[3][16][17];

    const int tid = threadIdx.x;
    const int r = blockIdx.x >> 5, cg = blockIdx.x & 31;
    const int j0 = cg * 8, row0 = r * 16;

    // one-time: this WG's weight slice into LDS hi/lo bf16 B-fragments
    for (int idx = tid; idx < 3 * 8 * 64; idx += 256){
        int t = idx / 512;
        int kk = (idx >> 6) & 7;
        int ln = idx & 63;
        int qq = ln >> 4, nn = ln & 15;
#pragma unroll
        for (int jj = 0; jj < 8; ++jj){
            int k = kk * 32 + qq * 8 + jj;
            float v = 0.0f;
            if (t < 2){
                int ngl = (nn < 8) ? (t * 512 + j0 + nn) : (t * 512 + 256 + j0 + nn - 8);
                v = W_all[(int64_t)k * 1024 + ngl];
            } else if (nn < 8){
                v = W_d[(int64_t)k * 256 + j0 + nn];
            }
            short hi = f2bf_s(v);
            wf_hi[t][kk][ln][jj] = hi;
            wf_lo[t][kk][ln][jj] = f2bf_s(v - bf2f_s(hi));
        }
    }
    __syncthreads();

    const int lane = tid & 63, w = tid >> 6;
    const int q = lane >> 4, al15 = lane & 15;

    // owner-cell registers (w2/w3: tid2 in [0,128) owns (row0+tid2>>3, j0+(tid2&7)))
    const int tid2 = tid & 127;
    const int b_own = tid2 >> 3, jl_own = tid2 & 7;
    const int gb = row0 + b_own, gj = j0 + jl_own;
    float c_reg = 0.0f;
    float bf_ = 0, bi_ = 0, bo_ = 0, bg_ = 0, bd_ = 0;
    if (w >= 2){
        bf_ = W_all_b[gj];
        bi_ = W_all_b[256 + gj];
        bo_ = W_all_b[512 + gj];
        bg_ = W_all_b[768 + gj];
        bd_ = W_d_b[gj];
    }

    const unsigned long long TAGM   = 0xFFFCFFFFFFFCFFFFULL;  // clear tag bits per u32
    const unsigned long long TAGSEL = 0x0003000000030000ULL;

    for (int s = 0; s < 256; ++s){
        __syncthreads();   // A: prev-step Dg consumption done before rewrite

        if (w < 2){
            f32x4 acc0 = {0.f, 0.f, 0.f, 0.f}, acc1 = {0.f, 0.f, 0.f, 0.f};
            if (s > 0){
                const unsigned tagexp = (unsigned)((s - 1) & 3);
                const unsigned long long expw =
                    ((unsigned long long)tagexp << 16) | ((unsigned long long)tagexp << 48);
                unsigned long long* sp = (unsigned long long*)
                    ((w == 0 ? hring : cring) + (((s - 1) & 1) << 15) + (row0 + al15) * 256);
                unsigned long long d[32];
                for (unsigned round = 0; ; ++round){
                    if ((round & 7u) != 7u){
#pragma unroll
                        for (int kk = 0; kk < 8; ++kk)
#pragma unroll
                            for (int i = 0; i < 4; ++i)
                                d[kk * 4 + i] = __hip_atomic_load(
                                    &sp[kk * 16 + q * 4 + i],
                                    __ATOMIC_RELAXED, __HIP_MEMORY_SCOPE_AGENT);
                    } else {
                        // guaranteed-fresh RMW fallback round (staleness safety net)
#pragma unroll
                        for (int kk = 0; kk < 8; ++kk)
#pragma unroll
                            for (int i = 0; i < 4; ++i){
                                unsigned* pw = (unsigned*)&sp[kk * 16 + q * 4 + i];
                                unsigned lo = __hip_atomic_fetch_add(pw, 0u,
                                    __ATOMIC_RELAXED, __HIP_MEMORY_SCOPE_AGENT);
                                unsigned hi = __hip_atomic_fetch_add(pw + 1, 0u,
                                    __ATOMIC_RELAXED, __HIP_MEMORY_SCOPE_AGENT);
                                d[kk * 4 + i] = (unsigned long long)lo |
                                                ((unsigned long long)hi << 32);
                            }
                    }
                    unsigned long long bad = 0ull;
#pragma unroll
                    for (int t2 = 0; t2 < 32; ++t2)
                        bad |= (d[t2] ^ expw) & TAGSEL;
                    if (__all(bad == 0ull)) break;
                }
                if (w == 0){
#pragma unroll
                    for (int kk = 0; kk < 8; ++kk){
                        unsigned long long q0 = d[kk*4+0] & TAGM, q1 = d[kk*4+1] & TAGM;
                        unsigned long long q2 = d[kk*4+2] & TAGM, q3 = d[kk*4+3] & TAGM;
                        unsigned w0_=(unsigned)q0, w1_=(unsigned)(q0>>32);
                        unsigned w2_=(unsigned)q1, w3_=(unsigned)(q1>>32);
                        unsigned w4_=(unsigned)q2, w5_=(unsigned)(q2>>32);
                        unsigned w6_=(unsigned)q3, w7_=(unsigned)(q3>>32);
                        union { short8 v; unsigned u32[4]; } ah, al;
                        ah.u32[0]=__builtin_amdgcn_perm(w1_,w0_,0x05040100u);
                        ah.u32[1]=__builtin_amdgcn_perm(w3_,w2_,0x05040100u);
                        ah.u32[2]=__builtin_amdgcn_perm(w5_,w4_,0x05040100u);
                        ah.u32[3]=__builtin_amdgcn_perm(w7_,w6_,0x05040100u);
                        al.u32[0]=__builtin_amdgcn_perm(w1_,w0_,0x07060302u);
                        al.u32[1]=__builtin_amdgcn_perm(w3_,w2_,0x07060302u);
                        al.u32[2]=__builtin_amdgcn_perm(w5_,w4_,0x07060302u);
                        al.u32[3]=__builtin_amdgcn_perm(w7_,w6_,0x07060302u);
                        short8 bh0 = *(const short8*)&wf_hi[0][kk][lane][0];
                        short8 bl0 = *(const short8*)&wf_lo[0][kk][lane][0];
                        short8 bh1 = *(const short8*)&wf_hi[1][kk][lane][0];
                        short8 bl1 = *(const short8*)&wf_lo[1][kk][lane][0];
                        acc0 = __builtin_amdgcn_mfma_f32_16x16x32_bf16(ah.v, bh0, acc0, 0,0,0);
                        acc0 = __builtin_amdgcn_mfma_f32_16x16x32_bf16(ah.v, bl0, acc0, 0,0,0);
                        acc0 = __builtin_amdgcn_mfma_f32_16x16x32_bf16(al.v, bh0, acc0, 0,0,0);
                        acc1 = __builtin_amdgcn_mfma_f32_16x16x32_bf16(ah.v, bh1, acc1, 0,0,0);
                        acc1 = __builtin_amdgcn_mfma_f32_16x16x32_bf16(ah.v, bl1, acc1, 0,0,0);
                        acc1 = __builtin_amdgcn_mfma_f32_16x16x32_bf16(al.v, bh1, acc1, 0,0,0);
                    }
                } else {
#pragma unroll
                    for (int kk = 0; kk < 8; ++kk){
                        unsigned long long q0 = d[kk*4+0] & TAGM, q1 = d[kk*4+1] & TAGM;
                        unsigned long long q2 = d[kk*4+2] & TAGM, q3 = d[kk*4+3] & TAGM;
                        unsigned w0_=(unsigned)q0, w1_=(unsigned)(q0>>32);
                        unsigned w2_=(unsigned)q1, w3_=(unsigned)(q1>>32);
                        unsigned w4_=(unsigned)q2, w5_=(unsigned)(q2>>32);
                        unsigned w6_=(unsigned)q3, w7_=(unsigned)(q3>>32);
                        union { short8 v; unsigned u32[4]; } ah, al;
                        ah.u32[0]=__builtin_amdgcn_perm(w1_,w0_,0x05040100u);
                        ah.u32[1]=__builtin_amdgcn_perm(w3_,w2_,0x05040100u);
                        ah.u32[2]=__builtin_amdgcn_perm(w5_,w4_,0x05040100u);
                        ah.u32[3]=__builtin_amdgcn_perm(w7_,w6_,0x05040100u);
                        al.u32[0]=__builtin_amdgcn_perm(w1_,w0_,0x07060302u);
                        al.u32[1]=__builtin_amdgcn_perm(w3_,w2_,0x07060302u);
                        al.u32[2]=__builtin_amdgcn_perm(w5_,w4_,0x07060302u);
                        al.u32[3]=__builtin_amdgcn_perm(w7_,w6_,0x07060302u);
                        short8 bh2 = *(const short8*)&wf_hi[2][kk][lane][0];
                        short8 bl2 = *(const short8*)&wf_lo[2][kk][lane][0];
                        acc0 = __builtin_amdgcn_mfma_f32_16x16x32_bf16(ah.v, bh2, acc0, 0,0,0);
                        acc0 = __builtin_amdgcn_mfma_f32_16x16x32_bf16(ah.v, bl2, acc0, 0,0,0);
                        acc0 = __builtin_amdgcn_mfma_f32_16x16x32_bf16(al.v, bh2, acc0, 0,0,0);
                    }
                }
            }
#pragma unroll
            for (int rg = 0; rg < 4; ++rg){
                if (w == 0){
                    Dg[0][q * 4 + rg][al15] = acc0[rg];
                    Dg[1][q * 4 + rg][al15] = acc1[rg];
                } else {
                    Dg[2][q * 4 + rg][al15] = acc0[rg];
                }
            }
        } else {
            // u/tsp prefetch (overlaps w0/w1 state spin)
            float uf = 0, ui = 0, uo = 0, ug = 0, tt = 0;
            const float* urow = u + ((int64_t)s * 128 + gb) * 1024;
            uf = urow[gj];       ui = urow[256 + gj];
            uo = urow[512 + gj]; ug = urow[768 + gj];
            tt = tsp[gb * 256 + s];
            __syncthreads();   // B: Dg ready

            float fpre = Dg[0][b_own][jl_own]     + uf + bf_;
            float ipre = Dg[0][b_own][8 + jl_own] + ui + bi_;
            float opre = Dg[1][b_own][jl_own]     + uo + bo_;
            float gpre = Dg[1][b_own][8 + jl_own] + ug + bg_;
            float spre = Dg[2][b_own][jl_own]     + bd_;

            float cs1 = tanhf(spre);
            float cadj = (c_reg - cs1) + cs1 * tt;
            float fg = sigmoidf_(fpre);
            float ig = sigmoidf_(ipre);
            float og = sigmoidf_(opre);
            float gg = sigmoidf_(gpre);
            float cn = fg * cadj + ig * gg;
            float hn = og * tanhf(cn);
            c_reg = cn;

            unsigned tag = (unsigned)(s & 3);
            short chi = f2bf_s(cn);
            unsigned short clo = (unsigned short)f2bf_s(cn - bf2f_s(chi));
            unsigned cword = (unsigned)(unsigned short)chi |
                             (((unsigned)((clo & 0xFFFCu) | tag)) << 16);
            short hhi = f2bf_s(hn);
            unsigned short hlo = (unsigned short)f2bf_s(hn - bf2f_s(hhi));
            unsigned hword = (unsigned)(unsigned short)hhi |
                             (((unsigned)((hlo & 0xFFFCu) | tag)) << 16);
            int off = ((s & 1) << 15) + gb * 256 + gj;
            __hip_atomic_store(&cring[off], cword,
                               __ATOMIC_RELAXED, __HIP_MEMORY_SCOPE_AGENT);
            __hip_atomic_store(&hring[off], hword,
                               __ATOMIC_RELAXED, __HIP_MEMORY_SCOPE_AGENT);
            __builtin_nontemporal_store(hn, &feat[((int64_t)gb * 256 + s) * 256 + gj]);
            continue;   // barrier B already executed on this path
        }
        __syncthreads();   // B (w0/w1 path)
    }
}

// ---------- classifier: out[r] = feat[r,:] . cls_w + cls_b ----------
__global__ __launch_bounds__(256) void k_cls(
    const float* __restrict__ feat, const float* __restrict__ cls_w,
    const float* __restrict__ cls_b, float* __restrict__ out)
{
    int tid = threadIdx.x, lane = tid & 63, w = tid >> 6;
    int row = blockIdx.x * 4 + w;
    float4 v  = ((const float4*)(feat + (int64_t)row * 256))[lane];
    float4 cw = ((const float4*)cls_w)[lane];
    float d = v.x * cw.x + v.y * cw.y + v.z * cw.z + v.w * cw.w;
#pragma unroll
    for (int off = 32; off > 0; off >>= 1)
        d += __shfl_down(d, off, 64);
    if (lane == 0) out[row] = d + cls_b[0];
}

extern "C" void kernel_launch(void* const* d_in, const int* in_sizes, int n_in,
                              void* d_out, int out_size, void* d_ws, size_t ws_size,
                              hipStream_t stream) {
    const float* x      = (const float*)d_in[0];
    const float* stages = (const float*)d_in[1];
    const float* tsp    = (const float*)d_in[2];
    const float* se_w1  = (const float*)d_in[3];
    const float* se_b1  = (const float*)d_in[4];
    const float* se_w2  = (const float*)d_in[5];
    const float* se_b2  = (const float*)d_in[6];
    const float* se_w3  = (const float*)d_in[7];
    const float* se_b3  = (const float*)d_in[8];
    const float* W_all  = (const float*)d_in[9];
    const float* W_allb = (const float*)d_in[10];
    const float* U_w    = (const float*)d_in[11];
    const float* U_b    = (const float*)d_in[12];
    const float* W_d    = (const float*)d_in[13];
    const float* W_d_b  = (const float*)d_in[14];
    const float* cls_w  = (const float*)d_in[15];
    const float* cls_b  = (const float*)d_in[16];
    (void)in_sizes; (void)n_in; (void)out_size; (void)ws_size;

    float* out  = (float*)d_out;          // [32768]
    float* feat = out + 32768;            // [32768][256]

    char* ws = (char*)d_ws;
    unsigned* hring  = (unsigned*)(ws + 4096);        // 2*32768*4 = 262144
    unsigned* cring  = (unsigned*)(ws + 266240);      // 262144, ends 528384
    short*  stagesP  = (short*)  (ws + 532480);       // 32768*96*2    = 6291456
    short*  st1      = (short*)  (ws + 6823936);      // 32768*256*2   = 16777216
    short*  st2      = (short*)  (ws + 23601152);     // 32768*512*2   = 33554432
    short*  w1T      = (short*)  (ws + 57155584);     // 256*96*2
    short*  w2T      = (short*)  (ws + 57204736);     // 512*256*2
    short*  w3T      = (short*)  (ws + 57466880);     // 1024*512*2
    short*  UwT      = (short*)  (ws + 58515456);     // 1024*2048*2   = 4194304
    short*  xin      = (short*)  (ws + 62709760);     // 32768*2048*2  = 134217728 (s-major)
    float*  u        = (float*)  (ws + 196927488);    // 256*128*1024*4= 134217728

    // per-launch init: poison ring slabs with never-matching tags.
    // slot0 (expects tags {0,2}) poisoned 0x55 (tag 1); slot1 (expects {1,3})
    // poisoned 0x00 (tag 0). Ring is only ever accessed with atomic/coherent ops.
    hipMemsetAsync((char*)hring,          0x55, 131072, stream);
    hipMemsetAsync((char*)hring + 131072, 0x00, 131072, stream);
    hipMemsetAsync((char*)cring,          0x55, 131072, stream);
    hipMemsetAsync((char*)cring + 131072, 0x00, 131072, stream);

    // conversions (xin s-major: row = s*128+b)
    k_cvt_x<<<8388608 / 256, 256, 0, stream>>>(x, xin);
    k_cvt_stages<<<(32768 * 96) / 256, 256, 0, stream>>>(stages, stagesP);
    k_transpose<<<(256 * 96) / 256, 256, 0, stream>>>(se_w1, w1T, 67, 256, 96);
    k_transpose<<<(512 * 256) / 256, 256, 0, stream>>>(se_w2, w2T, 256, 512, 256);
    k_transpose<<<(1024 * 512) / 256, 256, 0, stream>>>(se_w3, w3T, 512, 1024, 512);
    k_transpose<<<(1024 * 2048) / 256, 256, 0, stream>>>(U_w, UwT, 2048, 1024, 2048);

    // stage MLP (b-major chain), st3 stores permuted into s-major xin cols [1024,2048)
    k_gemm<<<dim3(2, 256), 256, 0, stream>>>(stagesP, 96, w1T, 96, se_b1, 96, 1 | 2,
                                             nullptr, st1, 256);
    k_gemm<<<dim3(4, 256), 256, 0, stream>>>(st1, 256, w2T, 256, se_b2, 256, 1 | 2,
                                             nullptr, st2, 512);
    k_gemm<<<dim3(8, 256), 256, 0, stream>>>(st2, 512, w3T, 512, se_b3, 512, 1 | 2 | 8,
                                             nullptr, xin + 1024, 2048);

    // u = xin @ U_all_w + U_all_b; xin rows are s-major so plain f32 store
    // yields u[s][b][1024] directly. Full-machine dispatch (no co-residency).
    k_gemm<<<dim3(8, 256), 256, 0, stream>>>(xin, 2048, UwT, 2048, U_b, 2048, 0,
                                             u, nullptr, 1024);

    // sequential TLSTM scan (ring-tag protocol, writes feat)
    k_scan<<<256, 256, 0, stream>>>(W_all, W_allb, W_d, W_d_b, u, tsp,
                                    hring, cring, feat);

    // classifier
    k_cls<<<8192, 256, 0, stream>>>(feat, cls_w, cls_b, out);
}